// Round 18
// baseline (298.901 us; speedup 1.0000x reference)
//
#include <hip/hip_runtime.h>
#include <math.h>

#define NN   50000
#define IN_F 256
#define OUTF 32
#define NH   4
#define NE   800000
#define NM   2
#define NK   10
#define ND   128

#define NCB  782    // coarse dst buckets (64 dsts each)
#define CCAP 1280   // capacity per coarse bucket (mean 1024, sigma 32 -> 8 sigma)
#define DSH  6
#define DMSK 63
#define NSL  32     // merge1 slices per (h,m)
#define SLW  245    // keys per slice (32*245 >= 7820)
#define SPCAP 256   // special-record list per bucket (expected max ~10)

__device__ __forceinline__ float lrelu(float x){ return x >= 0.f ? x : 0.2f*x; }
__device__ __forceinline__ unsigned fmap(float f){
  unsigned u = __float_as_uint(f);
  return (u & 0x80000000u) ? ~u : (u | 0x80000000u);
}
__device__ __forceinline__ float funmap(unsigned u){
  return (u & 0x80000000u) ? __uint_as_float(u & 0x7FFFFFFFu) : __uint_as_float(~u);
}

// ---- precompute pl/pr
__global__ __launch_bounds__(256) void k_plpr(
    const float* __restrict__ fc0, const float* __restrict__ al0, const float* __restrict__ ar0,
    const float* __restrict__ fc1, const float* __restrict__ al1, const float* __restrict__ ar1,
    float* __restrict__ plpr)
{
  int idx = blockIdx.x*256 + threadIdx.x;
  if (idx >= 4096) return;
  int w  = idx & 127;
  int hh = (idx >> 7) & 3;
  int lr = (idx >> 9) & 1;
  int m  = (idx >> 10) & 1;
  int L  = (idx >> 11) & 1;
  const float* fc = L ? fc1 : fc0;
  const float* at = L ? (lr ? ar1 : al1) : (lr ? ar0 : al0);
  float s = 0.f;
  for (int f = 0; f < OUTF; f++)
    s += at[(m*NH + hh)*OUTF + f] * fc[((size_t)m*128 + hh*OUTF + f)*128 + w];
  plpr[idx] = s;
}

// ---- P2[q][k] = sum_w plpr0[q][w] * Wh[w][k]   (16 x 256)
__global__ __launch_bounds__(256) void k_p2(
    const float* __restrict__ plpr, const float* __restrict__ Whm, float* __restrict__ P2)
{
  int idx = blockIdx.x*256 + threadIdx.x;
  if (idx >= 16*256) return;
  int q = idx >> 8, k = idx & 255;
  float s = 0.f;
  for (int w = 0; w < 128; w++)
    s += plpr[q*128 + w] * Whm[(size_t)w*IN_F + k];
  P2[q*256 + k] = s;
}

// ---- el0/er0 = h @ P2^T : 64-row blocks, memory-bound (reads h once)
__global__ __launch_bounds__(256) void k_el(
    const float* __restrict__ hmat, const float* __restrict__ P2,
    float* __restrict__ el0, float* __restrict__ er0)
{
  __shared__ float hs[64][68];
  __shared__ float PL2[16][260];
  int tid = threadIdx.x;
  int r0 = blockIdx.x * 64;
  for (int i = tid; i < 16*64; i += 256){
    int q = i >> 6, k4 = i & 63;
    float4 v = ((const float4*)P2)[q*64 + k4];
    *(float4*)&PL2[q][k4*4] = v;
  }
  int r = tid >> 2, c = tid & 3;
  float a0 = 0.f, a1 = 0.f, a2 = 0.f, a3 = 0.f;
  for (int kc = 0; kc < IN_F; kc += 64){
#pragma unroll
    for (int it = 0; it < 4; it++){
      int item = it*256 + tid;
      int row = item >> 4, f4 = item & 15;
      int grow = r0 + row;
      float4 v = make_float4(0.f,0.f,0.f,0.f);
      if (grow < NN) v = ((const float4*)hmat)[(size_t)grow*64 + (kc >> 2) + f4];
      *(float4*)&hs[row][f4*4] = v;
    }
    __syncthreads();
#pragma unroll
    for (int k4 = 0; k4 < 16; k4++){
      float4 hv = *(const float4*)&hs[r][k4*4];
      float4 u0 = *(const float4*)&PL2[c*4+0][kc + k4*4];
      float4 u1 = *(const float4*)&PL2[c*4+1][kc + k4*4];
      float4 u2 = *(const float4*)&PL2[c*4+2][kc + k4*4];
      float4 u3 = *(const float4*)&PL2[c*4+3][kc + k4*4];
      a0 += hv.x*u0.x; a0 += hv.y*u0.y; a0 += hv.z*u0.z; a0 += hv.w*u0.w;
      a1 += hv.x*u1.x; a1 += hv.y*u1.y; a1 += hv.z*u1.z; a1 += hv.w*u1.w;
      a2 += hv.x*u2.x; a2 += hv.y*u2.y; a2 += hv.z*u2.z; a2 += hv.w*u2.w;
      a3 += hv.x*u3.x; a3 += hv.y*u3.y; a3 += hv.z*u3.z; a3 += hv.w*u3.w;
    }
    __syncthreads();
  }
  int row = r0 + r;
  if (row < NN){
    int m = c >> 1;
    float* dp = (c & 1) ? er0 : el0;
    *(float4*)&dp[((size_t)m*NN + row)*4] = make_float4(a0, a1, a2, a3);
  }
}

// ---- coarse radix partition (64 blocks/m: 128B tail segments, half the tail atomics)
__global__ __launch_bounds__(256) void k_part(
    const int* __restrict__ s0, const int* __restrict__ d0,
    const int* __restrict__ s1, const int* __restrict__ d1,
    unsigned* __restrict__ ccnt, unsigned long long* __restrict__ coarse)
{
  int m = blockIdx.y;
  const int* sp = m ? s1 : s0;
  const int* dp = m ? d1 : d0;
  __shared__ unsigned hist[NCB], base[NCB], cur[NCB];
  int tid = threadIdx.x;
  for (int j = tid; j < NCB; j += 256){ hist[j] = 0u; cur[j] = 0u; }
  __syncthreads();
  int per = (NE + gridDim.x - 1) / gridDim.x;
  int e0 = blockIdx.x * per;
  int e1 = e0 + per; if (e1 > NE) e1 = NE;
  for (int i = e0 + tid; i < e1; i += 256)
    atomicAdd(&hist[dp[i] >> DSH], 1u);
  __syncthreads();
  for (int j = tid; j < NCB; j += 256)
    base[j] = hist[j] ? atomicAdd(&ccnt[m*NCB + j], hist[j]) : 0u;
  __syncthreads();
  for (int i = e0 + tid; i < e1; i += 256){
    int d = dp[i];
    int b = d >> DSH;
    unsigned loc = atomicAdd(&cur[b], 1u);
    unsigned pos = base[b] + loc;
    if (pos < CCAP)
      coarse[((size_t)m*NCB + b)*CCAP + pos] =
          ((unsigned long long)(unsigned)i << 24)
        | ((unsigned long long)(unsigned)(d & DMSK) << 16)
        | (unsigned long long)(unsigned)sp[i];
  }
}

// ---- layer-1 fused: e/texp+meta cached in LDS; mxF/smvF hoisted per (dst,head)
__global__ __launch_bounds__(256) void k_fused(
    const unsigned* __restrict__ ccnt, const unsigned long long* __restrict__ coarse,
    const float* __restrict__ el, const float* __restrict__ er,
    unsigned long long* __restrict__ cand)
{
  int bb = blockIdx.x, m = blockIdx.y;
  const unsigned long long* ce = coarse + ((size_t)m*NCB + bb)*CCAP;
  unsigned cnt = ccnt[m*NCB + bb]; if (cnt > CCAP) cnt = CCAP;
  const float* elp = el + (size_t)m*NN*4;
  const float* erp = er + (size_t)m*NN*4;
  int tid = threadIdx.x;
  int h = tid & 3, es = tid >> 2;
  int dbase = bb << DSH;

  __shared__ float4 erL[64];
  __shared__ unsigned mxL[64][4];
  __shared__ unsigned long long smL[64][4];
  __shared__ float mxF[64][4], smvF[64][4];
  __shared__ unsigned metaL[CCAP];
  __shared__ unsigned long long smem_u64[CCAP*2];
  float* eL = (float*)smem_u64;
  unsigned long long (*cs)[NK] = (unsigned long long(*)[NK])smem_u64;

  if (tid < 64){
    int d = dbase + tid;
    erL[tid] = (d < NN) ? *(const float4*)&erp[(size_t)d*4] : make_float4(0.f,0.f,0.f,0.f);
  }
  { int j = tid; mxL[j>>2][j&3] = 0u; smL[j>>2][j&3] = 0ULL; }
  __syncthreads();

  // pass 1: 4-deep pipelined; e -> eL, meta -> metaL, per-dst max (mapped u32, exact)
  {
    unsigned p = es;
    for (; p + 192 < cnt; p += 256){
      unsigned long long v0 = ce[p], v1 = ce[p+64], v2 = ce[p+128], v3 = ce[p+192];
      float g0 = elp[(unsigned)(v0 & 0xFFFFULL)*4 + h];
      float g1 = elp[(unsigned)(v1 & 0xFFFFULL)*4 + h];
      float g2 = elp[(unsigned)(v2 & 0xFFFFULL)*4 + h];
      float g3 = elp[(unsigned)(v3 & 0xFFFFULL)*4 + h];
      unsigned d0 = (unsigned)((v0 >> 16) & 0xFFULL);
      unsigned d1 = (unsigned)((v1 >> 16) & 0xFFULL);
      unsigned d2 = (unsigned)((v2 >> 16) & 0xFFULL);
      unsigned d3 = (unsigned)((v3 >> 16) & 0xFFULL);
      float e0 = lrelu(g0 + ((const float*)&erL[d0])[h]);
      float e1 = lrelu(g1 + ((const float*)&erL[d1])[h]);
      float e2 = lrelu(g2 + ((const float*)&erL[d2])[h]);
      float e3 = lrelu(g3 + ((const float*)&erL[d3])[h]);
      eL[p*4 + h] = e0; eL[(p+64)*4 + h] = e1;
      eL[(p+128)*4 + h] = e2; eL[(p+192)*4 + h] = e3;
      if (h == 0){
        metaL[p]     = ((unsigned)(v0 >> 24) << 8) | d0;
        metaL[p+64]  = ((unsigned)(v1 >> 24) << 8) | d1;
        metaL[p+128] = ((unsigned)(v2 >> 24) << 8) | d2;
        metaL[p+192] = ((unsigned)(v3 >> 24) << 8) | d3;
      }
      atomicMax(&mxL[d0][h], fmap(e0));
      atomicMax(&mxL[d1][h], fmap(e1));
      atomicMax(&mxL[d2][h], fmap(e2));
      atomicMax(&mxL[d3][h], fmap(e3));
    }
    for (; p < cnt; p += 64){
      unsigned long long v = ce[p];
      unsigned src  = (unsigned)(v & 0xFFFFULL);
      unsigned dloc = (unsigned)((v >> 16) & 0xFFULL);
      float e = lrelu(elp[src*4 + h] + ((const float*)&erL[dloc])[h]);
      eL[p*4 + h] = e;
      if (h == 0) metaL[p] = ((unsigned)(v >> 24) << 8) | dloc;
      atomicMax(&mxL[dloc][h], fmap(e));
    }
  }
  __syncthreads();
  // hoist mx float (bit-exact funmap, once per (dst,head))
  { int d_ = tid >> 2, h_ = tid & 3; mxF[d_][h_] = funmap(mxL[d_][h_]); }
  __syncthreads();

  // pass 2: texp = expf(e - mx) once, write back to eL; fixed-point sum (commutative exact)
  for (unsigned p = es; p < cnt; p += 64){
    unsigned dloc = metaL[p] & 255u;
    float texp = expf(eL[p*4 + h] - mxF[dloc][h]);
    eL[p*4 + h] = texp;
    atomicAdd(&smL[dloc][h],
        (unsigned long long)llrint((double)texp * 1073741824.0));
  }
  __syncthreads();
  // hoist smv float (identical conversion, once per (dst,head))
  { int d_ = tid >> 2, h_ = tid & 3;
    smvF[d_][h_] = (float)((double)smL[d_][h_] * (1.0/1073741824.0)); }
  __syncthreads();

  // pass 3: av = texp/smv + per-thread top-10 — LDS floats only
  unsigned long long top[NK];
#pragma unroll
  for (int k = 0; k < NK; k++) top[k] = 0ULL;
  for (unsigned p = es; p < cnt; p += 64){
    unsigned mt = metaL[p];
    unsigned dloc = mt & 255u;
    unsigned eid  = mt >> 8;
    float av = eL[p*4 + h] / smvF[dloc][h];
    unsigned long long key = ((unsigned long long)__float_as_uint(av) << 32)
                           | (unsigned long long)(~eid);
    if (key > top[NK-1]){
#pragma unroll
      for (int k = 0; k < NK; k++){
        unsigned long long hi = key > top[k] ? key : top[k];
        unsigned long long lo = key > top[k] ? top[k] : key;
        top[k] = hi; key = lo;
      }
    }
  }
  __syncthreads();

  int row = h*64 + es;
#pragma unroll
  for (int k = 0; k < NK; k++) cs[row][k] = top[k];
  __syncthreads();
  int w = tid >> 6, lane = tid & 63;
  unsigned long long mytop[NK];
#pragma unroll
  for (int k = 0; k < NK; k++) mytop[k] = cs[w*64 + lane][k];
  unsigned long long best = 0ULL; int bp = -1;
#pragma unroll
  for (int k = 0; k < NK; k++) if (mytop[k] > best){ best = mytop[k]; bp = k; }
  for (int r = 0; r < NK; r++){
    unsigned long long b = best; int srcl = lane;
#pragma unroll
    for (int off = 32; off > 0; off >>= 1){
      unsigned long long ob = __shfl_down(b, off, 64);
      int os = __shfl_down(srcl, off, 64);
      if (ob > b){ b = ob; srcl = os; }
    }
    b = __shfl(b, 0, 64); srcl = __shfl(srcl, 0, 64);
    if (lane == 0) cand[(((size_t)m*NH + w)*NCB + blockIdx.x)*NK + r] = b;
    if (lane == srcl && bp >= 0){
#pragma unroll
      for (int k = 0; k < NK; k++) if (k == bp) mytop[k] = 0ULL;
      best = 0ULL; bp = -1;
#pragma unroll
      for (int k = 0; k < NK; k++) if (mytop[k] > best){ best = mytop[k]; bp = k; }
    }
  }
}

// ---- layer-2 fused: exploits exact sparsity of el2/er2 (zero except special rows)
__global__ __launch_bounds__(256) void k_fused2(
    const unsigned* __restrict__ ccnt, const unsigned long long* __restrict__ coarse,
    const float* __restrict__ el2g, const float* __restrict__ er2g,
    const int* __restrict__ idsA,
    unsigned long long* __restrict__ cand)
{
  int bb = blockIdx.x, m = blockIdx.y;
  const unsigned long long* ce = coarse + ((size_t)m*NCB + bb)*CCAP;
  int cnt = (int)ccnt[m*NCB + bb]; if (cnt > CCAP) cnt = CCAP;
  const float* elp = el2g + (size_t)m*NN*4;
  const float* erp = er2g + (size_t)m*NN*4;
  int tid = threadIdx.x;
  int dbase = bb << DSH;

  __shared__ unsigned sbm[1568];
  __shared__ float4 erL[64];
  __shared__ unsigned cntL[64], spCntD[64];
  __shared__ unsigned char spIdx[CCAP];
  __shared__ int spSrc[SPCAP], spDl[SPCAP], spCnt;
  __shared__ float mxF[64][4], smvF[64][4], avBg[64][4];
  __shared__ float avSp[SPCAP][4];
  __shared__ unsigned long long cs[256][NK];

  for (int i = tid; i < 1568; i += 256) sbm[i] = 0u;
  if (tid < 64){
    cntL[tid] = 0u; spCntD[tid] = 0u;
    int d = dbase + tid;
    erL[tid] = (d < NN) ? *(const float4*)&erp[(size_t)d*4] : make_float4(0.f,0.f,0.f,0.f);
  }
  if (tid == 0) spCnt = 0;
  __syncthreads();
  if (tid < 64){
    int v = idsA[m*64 + tid];
    if (v >= 0) atomicOr(&sbm[v >> 5], 1u << (v & 31));
  }
  __syncthreads();

  for (int p = tid; p < cnt; p += 256){
    unsigned long long v = ce[p];
    unsigned src  = (unsigned)(v & 0xFFFFULL);
    unsigned dloc = (unsigned)((v >> 16) & 0xFFULL);
    atomicAdd(&cntL[dloc], 1u);
    unsigned char si = 255;
    if ((sbm[src >> 5] >> (src & 31)) & 1u){
      int j = atomicAdd(&spCnt, 1);
      if (j < SPCAP){
        spSrc[j] = (int)src; spDl[j] = (int)dloc;
        si = (unsigned char)j;
        atomicAdd(&spCntD[dloc], 1u);
      }
    }
    spIdx[p] = si;
  }
  __syncthreads();

  int nsp = spCnt < SPCAP ? spCnt : SPCAP;
  {
    int dloc = tid >> 2, h = tid & 3;
    float erv = ((const float*)&erL[dloc])[h];
    float ebg = lrelu(0.f + erv);
    int nbg = (int)cntL[dloc] - (int)spCntD[dloc];
    float mx = (nbg > 0) ? ebg : -INFINITY;
    for (int j = 0; j < nsp; j++)
      if (spDl[j] == dloc)
        mx = fmaxf(mx, lrelu(elp[(size_t)spSrc[j]*4 + h] + erv));
    unsigned long long sm = 0ULL;
    float tbg = 0.f;
    if (nbg > 0){
      tbg = expf(ebg - mx);
      sm += (unsigned long long)nbg *
            (unsigned long long)llrint((double)tbg * 1073741824.0);
    }
    for (int j = 0; j < nsp; j++)
      if (spDl[j] == dloc){
        float es_ = lrelu(elp[(size_t)spSrc[j]*4 + h] + erv);
        sm += (unsigned long long)llrint((double)expf(es_ - mx) * 1073741824.0);
      }
    float smv = (float)((double)sm * (1.0/1073741824.0));
    mxF[dloc][h] = mx; smvF[dloc][h] = smv;
    avBg[dloc][h] = (cntL[dloc] > 0 && nbg > 0) ? (tbg / smv) : 0.f;
  }
  __syncthreads();
  for (int t = tid; t < nsp*4; t += 256){
    int j = t >> 2, h = t & 3;
    int dloc = spDl[j];
    float erv = ((const float*)&erL[dloc])[h];
    float es_ = lrelu(elp[(size_t)spSrc[j]*4 + h] + erv);
    avSp[j][h] = expf(es_ - mxF[dloc][h]) / smvF[dloc][h];
  }
  __syncthreads();

  int h = tid & 3, es = tid >> 2;
  unsigned long long top[NK];
#pragma unroll
  for (int k = 0; k < NK; k++) top[k] = 0ULL;
  for (int p = es; p < cnt; p += 64){
    unsigned long long v = ce[p];
    unsigned dloc = (unsigned)((v >> 16) & 0xFFULL);
    unsigned eid  = (unsigned)(v >> 24);
    unsigned char si = spIdx[p];
    float av = (si == 255) ? avBg[dloc][h] : avSp[si][h];
    unsigned long long key = ((unsigned long long)__float_as_uint(av) << 32)
                           | (unsigned long long)(~eid);
    if (key > top[NK-1]){
#pragma unroll
      for (int k = 0; k < NK; k++){
        unsigned long long hi = key > top[k] ? key : top[k];
        unsigned long long lo = key > top[k] ? top[k] : key;
        top[k] = hi; key = lo;
      }
    }
  }
  __syncthreads();

  int row = h*64 + es;
#pragma unroll
  for (int k = 0; k < NK; k++) cs[row][k] = top[k];
  __syncthreads();
  int w = tid >> 6, lane = tid & 63;
  unsigned long long mytop[NK];
#pragma unroll
  for (int k = 0; k < NK; k++) mytop[k] = cs[w*64 + lane][k];
  unsigned long long best = 0ULL; int bp = -1;
#pragma unroll
  for (int k = 0; k < NK; k++) if (mytop[k] > best){ best = mytop[k]; bp = k; }
  for (int r = 0; r < NK; r++){
    unsigned long long b = best; int srcl = lane;
#pragma unroll
    for (int off = 32; off > 0; off >>= 1){
      unsigned long long ob = __shfl_down(b, off, 64);
      int os = __shfl_down(srcl, off, 64);
      if (ob > b){ b = ob; srcl = os; }
    }
    b = __shfl(b, 0, 64); srcl = __shfl(srcl, 0, 64);
    if (lane == 0) cand[(((size_t)m*NH + w)*NCB + blockIdx.x)*NK + r] = b;
    if (lane == srcl && bp >= 0){
#pragma unroll
      for (int k = 0; k < NK; k++) if (k == bp) mytop[k] = 0ULL;
      best = 0ULL; bp = -1;
#pragma unroll
      for (int k = 0; k < NK; k++) if (mytop[k] > best){ best = mytop[k]; bp = k; }
    }
  }
}

// ---- merge level 1
__global__ __launch_bounds__(256) void k_merge1(
    const unsigned long long* __restrict__ cand,
    unsigned long long* __restrict__ cand2)
{
  int hh = blockIdx.x, m = blockIdx.y, z = blockIdx.z;
  int tid = threadIdx.x;
  const unsigned long long* cp = cand + ((size_t)m*NH + hh)*((size_t)NCB*NK);
  int start = z*SLW;
  int end = start + SLW; if (end > NCB*NK) end = NCB*NK;
  unsigned long long mykey = (start + tid < end) ? cp[start + tid] : 0ULL;

  __shared__ unsigned long long red[256];
  __shared__ int redpos[256];
  for (int r = 0; r < NK; r++){
    red[tid] = mykey; redpos[tid] = tid;
    __syncthreads();
    for (int st = 128; st > 0; st >>= 1){
      if (tid < st && red[tid+st] > red[tid]){ red[tid] = red[tid+st]; redpos[tid] = redpos[tid+st]; }
      __syncthreads();
    }
    if (tid == 0)
      cand2[(((size_t)m*NH + hh)*NSL + z)*NK + r] = red[0];
    int winner = redpos[0];
    __syncthreads();
    if (tid == winner) mykey = 0ULL;
  }
}

// ---- merge level 2: 8 blocks x 512 threads
__global__ __launch_bounds__(512) void k_merge2(
    const unsigned long long* __restrict__ cand2,
    unsigned long long* __restrict__ selg)
{
  int hh = blockIdx.x, m = blockIdx.y;
  int tid = threadIdx.x;
  const unsigned long long* cp = cand2 + ((size_t)m*NH + hh)*((size_t)NSL*NK);
  unsigned long long mykey = (tid < NSL*NK) ? cp[tid] : 0ULL;

  __shared__ unsigned long long red[512];
  __shared__ int redpos[512];
  for (int r = 0; r < NK; r++){
    red[tid] = mykey; redpos[tid] = tid;
    __syncthreads();
    for (int st = 256; st > 0; st >>= 1){
      if (tid < st && red[tid+st] > red[tid]){ red[tid] = red[tid+st]; redpos[tid] = redpos[tid+st]; }
      __syncthreads();
    }
    if (tid == 0)
      selg[((size_t)m*NH + hh)*NK + r] = red[0];
    int winner = redpos[0];
    __syncthreads();
    if (tid == winner) mykey = 0ULL;
  }
}

// ---- selA: scores + ballot slot assignment
__global__ __launch_bounds__(256) void k_selA(
    const unsigned long long* __restrict__ selg,
    const int* __restrict__ s0, const int* __restrict__ d0,
    const int* __restrict__ s1, const int* __restrict__ d1,
    const int* __restrict__ idsA,
    int* __restrict__ idsOut, int4* __restrict__ selinfo, int layer)
{
  int m = blockIdx.x;
  int tid = threadIdx.x;
  const int* sp = m ? s1 : s0;
  const int* dp = m ? d1 : d0;
  int wv = tid >> 6, lane = tid & 63;

  __shared__ float scL[NH][NK];
  __shared__ int snL[NH][NK], dL[NH][NK];
  __shared__ int slotOf[NH][NK], srcOf[NH][NK];

  if (tid < NH*NK){
    int h = tid / NK, k = tid % NK;
    unsigned long long s = selg[((size_t)m*NH + h)*NK + k];
    int e = (int)(~(unsigned)(s & 0xFFFFFFFFULL));
    snL[h][k] = sp[e];
    dL[h][k]  = dp[e];
  }
  __syncthreads();

  if (tid < NH){
    float v0 = __uint_as_float((unsigned)(selg[((size_t)m*NH + tid)*NK + 0] >> 32));
    float p[NK]; float sum = 0.f;
#pragma unroll
    for (int k = 0; k < NK; k++){
      float v = __uint_as_float((unsigned)(selg[((size_t)m*NH + tid)*NK + k] >> 32));
      p[k] = expf(v - v0); sum += p[k];
    }
#pragma unroll
    for (int k = 0; k < NK; k++) scL[tid][k] = p[k] / sum;
  }

  if (wv == 0){
    int myA = -1;
    if (layer) myA = idsA[m*64 + lane];
    int myid = -1;
    int cnt = 0;
    for (int h = 0; h < NH; h++){
      for (int k = 0; k < NK; k++){
        int sn = snL[h][k], d = dL[h][k];
        int srcslot = sn;
        bool ok = true;
        if (layer){
          unsigned long long mb = __ballot(myA == sn);
          if (mb) srcslot = __ffsll(mb) - 1;
          else ok = false;
        }
        int slot = -1;
        if (ok){
          unsigned long long mm = __ballot(lane < cnt && myid == d);
          if (mm) slot = __ffsll(mm) - 1;
          else { slot = cnt; if (lane == cnt) myid = d; cnt++; }
        }
        if (lane == 0){ slotOf[h][k] = slot; srcOf[h][k] = srcslot; }
      }
    }
    idsOut[m*64 + lane] = (lane < cnt) ? myid : -1;
  }
  __syncthreads();

  if (tid < NH*NK){
    int h = tid / NK, k = tid % NK;
    selinfo[((size_t)m*NH + h)*NK + k] =
        make_int4(snL[h][k], slotOf[h][k], srcOf[h][k], __float_as_int(scL[h][k]));
  }
}

// ---- selB: per (h,m) block — on-demand wh rows (layer 0), parallel dsum, exact-order scatter
__global__ __launch_bounds__(256) void k_selB(
    const int4* __restrict__ selinfo,
    const float* __restrict__ hmat, const float* __restrict__ Whm,
    const float* __restrict__ ftsrc,  // layer1: vals0
    const float* __restrict__ fcW,
    float* __restrict__ valsOut, int layer)
{
  int h = blockIdx.x, m = blockIdx.y;
  int tid = threadIdx.x;
  __shared__ int sn10[NK], slot10[NK], srcsl10[NK];
  __shared__ float sc10[NK];
  __shared__ float hs10[NK][260];
  __shared__ float whL10[NK][132];
  __shared__ float dsumL[NK][32];

  if (tid < NK){
    int4 si = selinfo[((size_t)m*NH + h)*NK + tid];
    sn10[tid] = si.x; slot10[tid] = si.y; srcsl10[tid] = si.z;
    sc10[tid] = __int_as_float(si.w);
  }
  __syncthreads();

  if (layer == 0){
    for (int t = tid; t < NK*64; t += 256){
      int e = t >> 6, k4 = t & 63;
      float4 v = ((const float4*)hmat)[(size_t)sn10[e]*64 + k4];
      *(float4*)&hs10[e][k4*4] = v;
    }
    __syncthreads();
    int w = tid & 127, rh = tid >> 7;
    float acc5[5];
#pragma unroll
    for (int i = 0; i < 5; i++) acc5[i] = 0.f;
    const float4* wp = (const float4*)&Whm[(size_t)w*IN_F];
    for (int k4 = 0; k4 < 64; k4++){
      float4 wv2 = wp[k4];
#pragma unroll
      for (int i = 0; i < 5; i++){
        float4 hv = *(const float4*)&hs10[rh + 2*i][k4*4];
        acc5[i] += hv.x*wv2.x; acc5[i] += hv.y*wv2.y;
        acc5[i] += hv.z*wv2.z; acc5[i] += hv.w*wv2.w;
      }
    }
#pragma unroll
    for (int i = 0; i < 5; i++) whL10[rh + 2*i][w] = acc5[i];
    __syncthreads();
  }

  for (int t = tid; t < NK*32; t += 256){
    int k = t >> 5, f = t & 31;
    float dsum = 0.f;
    if (slot10[k] >= 0){
      const float* x = layer ? (ftsrc + ((size_t)m*64 + srcsl10[k])*128) : &whL10[k][0];
      const float* wr = fcW + ((size_t)m*128 + h*OUTF + f)*128;
      for (int w = 0; w < 128; w++) dsum += x[w] * wr[w];
    }
    dsumL[k][f] = dsum;
  }
  __syncthreads();

  if (tid < OUTF){
    int f = tid;
    float* vals = valsOut + (size_t)m*64*128;
    for (int k = 0; k < NK; k++){
      int slot = slot10[k];
      if (slot < 0) continue;
      vals[(size_t)slot*128 + h*OUTF + f] += sc10[k] * dsumL[k][f];
    }
  }
}

// ---- elu on sparse rows; optionally compute layer-2 el2/er2 entries
__global__ __launch_bounds__(128) void k_elu2(
    const int* __restrict__ ids, float* __restrict__ vals,
    const float* __restrict__ plpr1,
    float* __restrict__ el2, float* __restrict__ er2, int doEl2)
{
  int slot = blockIdx.x, m = blockIdx.y, tid = threadIdx.x;
  float* row = vals + ((size_t)m*64 + slot)*128;
  float x = row[tid];
  row[tid] = x > 0.f ? x : expm1f(x);
  __syncthreads();
  if (!doEl2) return;
  int d = ids[m*64 + slot];
  if (d < 0) return;
  if (tid < 8){
    int lr = tid >> 2, hh = tid & 3;
    const float* P = plpr1 + (((size_t)m*2 + lr)*NH + hh)*128;
    float s = 0.f;
    for (int w = 0; w < 128; w++) s += row[w] * P[w];
    float* dp = lr ? er2 : el2;
    dp[((size_t)m*NN + d)*4 + hh] = s;
  }
}

// ---- semantic attention on special rows only (inlined first-occurrence dedupe)
__global__ __launch_bounds__(128) void k_final(
    const int* __restrict__ ids, const float* __restrict__ vals,
    const float* __restrict__ Wp1, const float* __restrict__ bp1, const float* __restrict__ Wp2,
    float c0, float c1, float* __restrict__ out)
{
  int j = blockIdx.x;
  int n = ids[j];
  if (n < 0) return;
  for (int q = 0; q < j; q++) if (ids[q] == n) return;
  int tid = threadIdx.x;
  __shared__ float z[2][128];
  __shared__ int slots[4];
  if (tid < 4){
    int sl = -1;
    const int* base = ids + tid*64;
    for (int q = 0; q < 64; q++) if (base[q] == n){ sl = q; break; }
    slots[tid] = sl;
  }
  __syncthreads();
#pragma unroll
  for (int m = 0; m < 2; m++){
    int sa = slots[m], sb = slots[2 + m];
    float av = sa >= 0 ? vals[((size_t)m*64 + sa)*128 + tid] : 0.f;
    float bv = sb >= 0 ? vals[((size_t)(2 + m)*64 + sb)*128 + tid] : 0.f;
    z[m][tid] = c0*av + c1*bv;
  }
  __syncthreads();
  float a0 = bp1[tid], a1 = a0;
  const float* wr = Wp1 + (size_t)tid*128;
  for (int w = 0; w < 128; w++){
    float wv = wr[w];
    a0 += z[0][w]*wv;
    a1 += z[1][w]*wv;
  }
  float t0 = tanhf(a0), t1 = tanhf(a1);
  float w2v = Wp2[tid];
  __shared__ float r0[128], r1[128];
  r0[tid] = t0*w2v; r1[tid] = t1*w2v;
  __syncthreads();
  for (int st = 64; st > 0; st >>= 1){
    if (tid < st){ r0[tid] += r0[tid+st]; r1[tid] += r1[tid+st]; }
    __syncthreads();
  }
  __shared__ float b0s, b1s;
  if (tid == 0){
    float w0 = r0[0], w1 = r1[0];
    float mxv = fmaxf(w0, w1);
    float e0 = expf(w0 - mxv), e1 = expf(w1 - mxv);
    float s = e0 + e1;
    b0s = e0/s; b1s = e1/s;
  }
  __syncthreads();
  out[(size_t)n*ND + tid] = b0s*z[0][tid] + b1s*z[1][tid];
}

extern "C" void kernel_launch(void* const* d_in, const int* in_sizes, int n_in,
                              void* d_out, int out_size, void* d_ws, size_t ws_size,
                              hipStream_t stream)
{
  const float* h    = (const float*)d_in[0];
  const int*   src0 = (const int*)d_in[1];
  const int*   dst0 = (const int*)d_in[2];
  const int*   src1 = (const int*)d_in[3];
  const int*   dst1 = (const int*)d_in[4];
  const float* Wh   = (const float*)d_in[5];
  const float* fc0  = (const float*)d_in[6];
  const float* al0  = (const float*)d_in[7];
  const float* ar0  = (const float*)d_in[8];
  const float* fc1  = (const float*)d_in[9];
  const float* al1  = (const float*)d_in[10];
  const float* ar1  = (const float*)d_in[11];
  const float* Wp1  = (const float*)d_in[12];
  const float* bp1  = (const float*)d_in[13];
  const float* Wp2  = (const float*)d_in[14];
  float* out = (float*)d_out;

  char* ws = (char*)d_ws;
  size_t off = 0;
  auto alloc = [&](size_t b){ size_t o = off; off = (off + b + 255) & ~(size_t)255; return o; };
  size_t o_el0    = alloc((size_t)NM*NN*4*4);
  size_t o_er0    = alloc((size_t)NM*NN*4*4);
  size_t o_plpr   = alloc(4096*4);
  size_t o_p2     = alloc(16*256*4);
  size_t o_cand   = alloc((size_t)NM*NH*NCB*NK*8);
  size_t o_cand2  = alloc((size_t)NM*NH*NSL*NK*8);
  size_t o_selg   = alloc((size_t)NM*NH*NK*8);
  size_t o_selinf = alloc((size_t)NM*NH*NK*16);
  size_t o_coarse = alloc((size_t)NM*NCB*CCAP*8);
  size_t o_zs     = off;                       // ---- zeroed region start
  size_t o_ccnt   = alloc((size_t)NM*NCB*4);
  size_t o_el2    = alloc((size_t)NM*NN*4*4);
  size_t o_er2    = alloc((size_t)NM*NN*4*4);
  size_t o_vals   = alloc((size_t)2*NM*64*128*4);
  size_t zlen = off - o_zs;                    // ---- zeroed region end
  size_t o_ids    = alloc((size_t)2*NM*64*4);
  (void)ws_size; (void)in_sizes; (void)n_in;

  float* el0p  = (float*)(ws + o_el0);
  float* er0p  = (float*)(ws + o_er0);
  float* plprp = (float*)(ws + o_plpr);
  float* p2p   = (float*)(ws + o_p2);
  unsigned long long* candp  = (unsigned long long*)(ws + o_cand);
  unsigned long long* cand2p = (unsigned long long*)(ws + o_cand2);
  unsigned long long* selgp  = (unsigned long long*)(ws + o_selg);
  int4* selinfp = (int4*)(ws + o_selinf);
  unsigned long long* coarsep = (unsigned long long*)(ws + o_coarse);
  unsigned* ccntp = (unsigned*)(ws + o_ccnt);
  float* el2p  = (float*)(ws + o_el2);
  float* er2p  = (float*)(ws + o_er2);
  float* valsp = (float*)(ws + o_vals);
  int*   idsp  = (int*)(ws + o_ids);
  float* vals0p = valsp;
  float* vals1p = valsp + (size_t)NM*64*128;
  int* ids0p = idsp;
  int* ids1p = idsp + NM*64;
  float* plpr1p = plprp + 2048;

  double x1 = 1.0 / (2.0 * sqrt(2.0));
  double ssum = 1.0 + x1;
  float c0 = (float)(1.0/ssum), c1 = (float)(x1/ssum);

  hipMemsetAsync(d_out, 0, (size_t)out_size*sizeof(float), stream);
  hipMemsetAsync(ws + o_zs, 0, zlen, stream);

  k_plpr<<<16, 256, 0, stream>>>(fc0, al0, ar0, fc1, al1, ar1, plprp);
  k_p2<<<16, 256, 0, stream>>>(plprp, Wh, p2p);
  k_el<<<(NN + 63)/64, 256, 0, stream>>>(h, p2p, el0p, er0p);

  k_part<<<dim3(64, NM), 256, 0, stream>>>(src0, dst0, src1, dst1, ccntp, coarsep);

  dim3 gf(NCB, NM);
  dim3 gm1(NH, NM, NSL);
  dim3 gm2(NH, NM);
  dim3 gb(NH, NM);
  dim3 ge(64, NM);

  // ---- layer 1
  k_fused<<<gf, 256, 0, stream>>>(ccntp, coarsep, el0p, er0p, candp);
  k_merge1<<<gm1, 256, 0, stream>>>(candp, cand2p);
  k_merge2<<<gm2, 512, 0, stream>>>(cand2p, selgp);
  k_selA<<<NM, 256, 0, stream>>>(selgp, src0, dst0, src1, dst1,
                                 (const int*)nullptr, ids0p, selinfp, 0);
  k_selB<<<gb, 256, 0, stream>>>(selinfp, h, Wh, (const float*)nullptr, fc0, vals0p, 0);
  k_elu2<<<ge, 128, 0, stream>>>(ids0p, vals0p, plpr1p, el2p, er2p, 1);

  // ---- layer 2 (sparsity-specialized fused kernel)
  k_fused2<<<gf, 256, 0, stream>>>(ccntp, coarsep, el2p, er2p, ids0p, candp);
  k_merge1<<<gm1, 256, 0, stream>>>(candp, cand2p);
  k_merge2<<<gm2, 512, 0, stream>>>(cand2p, selgp);
  k_selA<<<NM, 256, 0, stream>>>(selgp, src0, dst0, src1, dst1,
                                 ids0p, ids1p, selinfp, 1);
  k_selB<<<gb, 256, 0, stream>>>(selinfp, h, Wh, vals0p, fc1, vals1p, 1);
  k_elu2<<<ge, 128, 0, stream>>>(ids1p, vals1p, plpr1p, el2p, er2p, 0);

  // ---- semantic attention on the sparse union
  k_final<<<256, 128, 0, stream>>>(idsp, valsp, Wp1, bp1, Wp2, c0, c1, out);
}

// Round 19
// 282.509 us; speedup vs baseline: 1.0580x; 1.0580x over previous
//
#include <hip/hip_runtime.h>
#include <math.h>

#define NN   50000
#define IN_F 256
#define OUTF 32
#define NH   4
#define NE   800000
#define NM   2
#define NK   10
#define ND   128

#define NCB  782    // coarse dst buckets (64 dsts each)
#define CCAP 1280   // capacity per coarse bucket (mean 1024, sigma 32 -> 8 sigma)
#define DSH  6
#define DMSK 63
#define NSL  32     // merge1 slices per (h,m)
#define SLW  245    // keys per slice (32*245 >= 7820)
#define SPCAP 256   // special-record list per bucket (expected max ~10)

__device__ __forceinline__ float lrelu(float x){ return x >= 0.f ? x : 0.2f*x; }
__device__ __forceinline__ unsigned fmap(float f){
  unsigned u = __float_as_uint(f);
  return (u & 0x80000000u) ? ~u : (u | 0x80000000u);
}
__device__ __forceinline__ float funmap(unsigned u){
  return (u & 0x80000000u) ? __uint_as_float(u & 0x7FFFFFFFu) : __uint_as_float(~u);
}

// ---- precompute pl/pr
__global__ __launch_bounds__(256) void k_plpr(
    const float* __restrict__ fc0, const float* __restrict__ al0, const float* __restrict__ ar0,
    const float* __restrict__ fc1, const float* __restrict__ al1, const float* __restrict__ ar1,
    float* __restrict__ plpr)
{
  int idx = blockIdx.x*256 + threadIdx.x;
  if (idx >= 4096) return;
  int w  = idx & 127;
  int hh = (idx >> 7) & 3;
  int lr = (idx >> 9) & 1;
  int m  = (idx >> 10) & 1;
  int L  = (idx >> 11) & 1;
  const float* fc = L ? fc1 : fc0;
  const float* at = L ? (lr ? ar1 : al1) : (lr ? ar0 : al0);
  float s = 0.f;
  for (int f = 0; f < OUTF; f++)
    s += at[(m*NH + hh)*OUTF + f] * fc[((size_t)m*128 + hh*OUTF + f)*128 + w];
  plpr[idx] = s;
}

// ---- P2[q][k] = sum_w plpr0[q][w] * Wh[w][k]   (16 x 256)
__global__ __launch_bounds__(256) void k_p2(
    const float* __restrict__ plpr, const float* __restrict__ Whm, float* __restrict__ P2)
{
  int idx = blockIdx.x*256 + threadIdx.x;
  if (idx >= 16*256) return;
  int q = idx >> 8, k = idx & 255;
  float s = 0.f;
  for (int w = 0; w < 128; w++)
    s += plpr[q*128 + w] * Whm[(size_t)w*IN_F + k];
  P2[q*256 + k] = s;
}

// ---- el0/er0 = h @ P2^T : 64-row blocks, memory-bound (reads h once)
__global__ __launch_bounds__(256) void k_el(
    const float* __restrict__ hmat, const float* __restrict__ P2,
    float* __restrict__ el0, float* __restrict__ er0)
{
  __shared__ float hs[64][68];
  __shared__ float PL2[16][260];
  int tid = threadIdx.x;
  int r0 = blockIdx.x * 64;
  for (int i = tid; i < 16*64; i += 256){
    int q = i >> 6, k4 = i & 63;
    float4 v = ((const float4*)P2)[q*64 + k4];
    *(float4*)&PL2[q][k4*4] = v;
  }
  int r = tid >> 2, c = tid & 3;
  float a0 = 0.f, a1 = 0.f, a2 = 0.f, a3 = 0.f;
  for (int kc = 0; kc < IN_F; kc += 64){
#pragma unroll
    for (int it = 0; it < 4; it++){
      int item = it*256 + tid;
      int row = item >> 4, f4 = item & 15;
      int grow = r0 + row;
      float4 v = make_float4(0.f,0.f,0.f,0.f);
      if (grow < NN) v = ((const float4*)hmat)[(size_t)grow*64 + (kc >> 2) + f4];
      *(float4*)&hs[row][f4*4] = v;
    }
    __syncthreads();
#pragma unroll
    for (int k4 = 0; k4 < 16; k4++){
      float4 hv = *(const float4*)&hs[r][k4*4];
      float4 u0 = *(const float4*)&PL2[c*4+0][kc + k4*4];
      float4 u1 = *(const float4*)&PL2[c*4+1][kc + k4*4];
      float4 u2 = *(const float4*)&PL2[c*4+2][kc + k4*4];
      float4 u3 = *(const float4*)&PL2[c*4+3][kc + k4*4];
      a0 += hv.x*u0.x; a0 += hv.y*u0.y; a0 += hv.z*u0.z; a0 += hv.w*u0.w;
      a1 += hv.x*u1.x; a1 += hv.y*u1.y; a1 += hv.z*u1.z; a1 += hv.w*u1.w;
      a2 += hv.x*u2.x; a2 += hv.y*u2.y; a2 += hv.z*u2.z; a2 += hv.w*u2.w;
      a3 += hv.x*u3.x; a3 += hv.y*u3.y; a3 += hv.z*u3.z; a3 += hv.w*u3.w;
    }
    __syncthreads();
  }
  int row = r0 + r;
  if (row < NN){
    int m = c >> 1;
    float* dp = (c & 1) ? er0 : el0;
    *(float4*)&dp[((size_t)m*NN + row)*4] = make_float4(a0, a1, a2, a3);
  }
}

// ---- coarse radix partition (256 blocks/m: proven configuration)
__global__ __launch_bounds__(256) void k_part(
    const int* __restrict__ s0, const int* __restrict__ d0,
    const int* __restrict__ s1, const int* __restrict__ d1,
    unsigned* __restrict__ ccnt, unsigned long long* __restrict__ coarse)
{
  int m = blockIdx.y;
  const int* sp = m ? s1 : s0;
  const int* dp = m ? d1 : d0;
  __shared__ unsigned hist[NCB], base[NCB], cur[NCB];
  int tid = threadIdx.x;
  for (int j = tid; j < NCB; j += 256){ hist[j] = 0u; cur[j] = 0u; }
  __syncthreads();
  int per = (NE + gridDim.x - 1) / gridDim.x;
  int e0 = blockIdx.x * per;
  int e1 = e0 + per; if (e1 > NE) e1 = NE;
  for (int i = e0 + tid; i < e1; i += 256)
    atomicAdd(&hist[dp[i] >> DSH], 1u);
  __syncthreads();
  for (int j = tid; j < NCB; j += 256)
    base[j] = hist[j] ? atomicAdd(&ccnt[m*NCB + j], hist[j]) : 0u;
  __syncthreads();
  for (int i = e0 + tid; i < e1; i += 256){
    int d = dp[i];
    int b = d >> DSH;
    unsigned loc = atomicAdd(&cur[b], 1u);
    unsigned pos = base[b] + loc;
    if (pos < CCAP)
      coarse[((size_t)m*NCB + b)*CCAP + pos] =
          ((unsigned long long)(unsigned)i << 24)
        | ((unsigned long long)(unsigned)(d & DMSK) << 16)
        | (unsigned long long)(unsigned)sp[i];
  }
}

// ---- layer-1 fused: e/texp+meta cached in LDS; mxF/smvF hoisted per (dst,head)
__global__ __launch_bounds__(256) void k_fused(
    const unsigned* __restrict__ ccnt, const unsigned long long* __restrict__ coarse,
    const float* __restrict__ el, const float* __restrict__ er,
    unsigned long long* __restrict__ cand)
{
  int bb = blockIdx.x, m = blockIdx.y;
  const unsigned long long* ce = coarse + ((size_t)m*NCB + bb)*CCAP;
  unsigned cnt = ccnt[m*NCB + bb]; if (cnt > CCAP) cnt = CCAP;
  const float* elp = el + (size_t)m*NN*4;
  const float* erp = er + (size_t)m*NN*4;
  int tid = threadIdx.x;
  int h = tid & 3, es = tid >> 2;
  int dbase = bb << DSH;

  __shared__ float4 erL[64];
  __shared__ unsigned mxL[64][4];
  __shared__ unsigned long long smL[64][4];
  __shared__ float mxF[64][4], smvF[64][4];
  __shared__ unsigned metaL[CCAP];
  __shared__ unsigned long long smem_u64[CCAP*2];
  float* eL = (float*)smem_u64;
  unsigned long long (*cs)[NK] = (unsigned long long(*)[NK])smem_u64;

  if (tid < 64){
    int d = dbase + tid;
    erL[tid] = (d < NN) ? *(const float4*)&erp[(size_t)d*4] : make_float4(0.f,0.f,0.f,0.f);
  }
  { int j = tid; mxL[j>>2][j&3] = 0u; smL[j>>2][j&3] = 0ULL; }
  __syncthreads();

  // pass 1: 4-deep pipelined; e -> eL, meta -> metaL, per-dst max (mapped u32, exact)
  {
    unsigned p = es;
    for (; p + 192 < cnt; p += 256){
      unsigned long long v0 = ce[p], v1 = ce[p+64], v2 = ce[p+128], v3 = ce[p+192];
      float g0 = elp[(unsigned)(v0 & 0xFFFFULL)*4 + h];
      float g1 = elp[(unsigned)(v1 & 0xFFFFULL)*4 + h];
      float g2 = elp[(unsigned)(v2 & 0xFFFFULL)*4 + h];
      float g3 = elp[(unsigned)(v3 & 0xFFFFULL)*4 + h];
      unsigned d0 = (unsigned)((v0 >> 16) & 0xFFULL);
      unsigned d1 = (unsigned)((v1 >> 16) & 0xFFULL);
      unsigned d2 = (unsigned)((v2 >> 16) & 0xFFULL);
      unsigned d3 = (unsigned)((v3 >> 16) & 0xFFULL);
      float e0 = lrelu(g0 + ((const float*)&erL[d0])[h]);
      float e1 = lrelu(g1 + ((const float*)&erL[d1])[h]);
      float e2 = lrelu(g2 + ((const float*)&erL[d2])[h]);
      float e3 = lrelu(g3 + ((const float*)&erL[d3])[h]);
      eL[p*4 + h] = e0; eL[(p+64)*4 + h] = e1;
      eL[(p+128)*4 + h] = e2; eL[(p+192)*4 + h] = e3;
      if (h == 0){
        metaL[p]     = ((unsigned)(v0 >> 24) << 8) | d0;
        metaL[p+64]  = ((unsigned)(v1 >> 24) << 8) | d1;
        metaL[p+128] = ((unsigned)(v2 >> 24) << 8) | d2;
        metaL[p+192] = ((unsigned)(v3 >> 24) << 8) | d3;
      }
      atomicMax(&mxL[d0][h], fmap(e0));
      atomicMax(&mxL[d1][h], fmap(e1));
      atomicMax(&mxL[d2][h], fmap(e2));
      atomicMax(&mxL[d3][h], fmap(e3));
    }
    for (; p < cnt; p += 64){
      unsigned long long v = ce[p];
      unsigned src  = (unsigned)(v & 0xFFFFULL);
      unsigned dloc = (unsigned)((v >> 16) & 0xFFULL);
      float e = lrelu(elp[src*4 + h] + ((const float*)&erL[dloc])[h]);
      eL[p*4 + h] = e;
      if (h == 0) metaL[p] = ((unsigned)(v >> 24) << 8) | dloc;
      atomicMax(&mxL[dloc][h], fmap(e));
    }
  }
  __syncthreads();
  { int d_ = tid >> 2, h_ = tid & 3; mxF[d_][h_] = funmap(mxL[d_][h_]); }
  __syncthreads();

  // pass 2: texp = expf(e - mx) once, write back to eL; fixed-point sum (commutative exact)
  for (unsigned p = es; p < cnt; p += 64){
    unsigned dloc = metaL[p] & 255u;
    float texp = expf(eL[p*4 + h] - mxF[dloc][h]);
    eL[p*4 + h] = texp;
    atomicAdd(&smL[dloc][h],
        (unsigned long long)llrint((double)texp * 1073741824.0));
  }
  __syncthreads();
  { int d_ = tid >> 2, h_ = tid & 3;
    smvF[d_][h_] = (float)((double)smL[d_][h_] * (1.0/1073741824.0)); }
  __syncthreads();

  // pass 3: av = texp/smv + per-thread top-10 — LDS floats only
  unsigned long long top[NK];
#pragma unroll
  for (int k = 0; k < NK; k++) top[k] = 0ULL;
  for (unsigned p = es; p < cnt; p += 64){
    unsigned mt = metaL[p];
    unsigned dloc = mt & 255u;
    unsigned eid  = mt >> 8;
    float av = eL[p*4 + h] / smvF[dloc][h];
    unsigned long long key = ((unsigned long long)__float_as_uint(av) << 32)
                           | (unsigned long long)(~eid);
    if (key > top[NK-1]){
#pragma unroll
      for (int k = 0; k < NK; k++){
        unsigned long long hi = key > top[k] ? key : top[k];
        unsigned long long lo = key > top[k] ? top[k] : key;
        top[k] = hi; key = lo;
      }
    }
  }
  __syncthreads();

  int row = h*64 + es;
#pragma unroll
  for (int k = 0; k < NK; k++) cs[row][k] = top[k];
  __syncthreads();
  int w = tid >> 6, lane = tid & 63;
  unsigned long long mytop[NK];
#pragma unroll
  for (int k = 0; k < NK; k++) mytop[k] = cs[w*64 + lane][k];
  unsigned long long best = 0ULL; int bp = -1;
#pragma unroll
  for (int k = 0; k < NK; k++) if (mytop[k] > best){ best = mytop[k]; bp = k; }
  for (int r = 0; r < NK; r++){
    unsigned long long b = best; int srcl = lane;
#pragma unroll
    for (int off = 32; off > 0; off >>= 1){
      unsigned long long ob = __shfl_down(b, off, 64);
      int os = __shfl_down(srcl, off, 64);
      if (ob > b){ b = ob; srcl = os; }
    }
    b = __shfl(b, 0, 64); srcl = __shfl(srcl, 0, 64);
    if (lane == 0) cand[(((size_t)m*NH + w)*NCB + blockIdx.x)*NK + r] = b;
    if (lane == srcl && bp >= 0){
#pragma unroll
      for (int k = 0; k < NK; k++) if (k == bp) mytop[k] = 0ULL;
      best = 0ULL; bp = -1;
#pragma unroll
      for (int k = 0; k < NK; k++) if (mytop[k] > best){ best = mytop[k]; bp = k; }
    }
  }
}

// ---- layer-2 fused: exploits exact sparsity of el2/er2 (zero except special rows)
__global__ __launch_bounds__(256) void k_fused2(
    const unsigned* __restrict__ ccnt, const unsigned long long* __restrict__ coarse,
    const float* __restrict__ el2g, const float* __restrict__ er2g,
    const int* __restrict__ idsA,
    unsigned long long* __restrict__ cand)
{
  int bb = blockIdx.x, m = blockIdx.y;
  const unsigned long long* ce = coarse + ((size_t)m*NCB + bb)*CCAP;
  int cnt = (int)ccnt[m*NCB + bb]; if (cnt > CCAP) cnt = CCAP;
  const float* elp = el2g + (size_t)m*NN*4;
  const float* erp = er2g + (size_t)m*NN*4;
  int tid = threadIdx.x;
  int dbase = bb << DSH;

  __shared__ unsigned sbm[1568];
  __shared__ float4 erL[64];
  __shared__ unsigned cntL[64], spCntD[64];
  __shared__ unsigned char spIdx[CCAP];
  __shared__ int spSrc[SPCAP], spDl[SPCAP], spCnt;
  __shared__ float mxF[64][4], smvF[64][4], avBg[64][4];
  __shared__ float avSp[SPCAP][4];
  __shared__ unsigned long long cs[256][NK];

  for (int i = tid; i < 1568; i += 256) sbm[i] = 0u;
  if (tid < 64){
    cntL[tid] = 0u; spCntD[tid] = 0u;
    int d = dbase + tid;
    erL[tid] = (d < NN) ? *(const float4*)&erp[(size_t)d*4] : make_float4(0.f,0.f,0.f,0.f);
  }
  if (tid == 0) spCnt = 0;
  __syncthreads();
  if (tid < 64){
    int v = idsA[m*64 + tid];
    if (v >= 0) atomicOr(&sbm[v >> 5], 1u << (v & 31));
  }
  __syncthreads();

  for (int p = tid; p < cnt; p += 256){
    unsigned long long v = ce[p];
    unsigned src  = (unsigned)(v & 0xFFFFULL);
    unsigned dloc = (unsigned)((v >> 16) & 0xFFULL);
    atomicAdd(&cntL[dloc], 1u);
    unsigned char si = 255;
    if ((sbm[src >> 5] >> (src & 31)) & 1u){
      int j = atomicAdd(&spCnt, 1);
      if (j < SPCAP){
        spSrc[j] = (int)src; spDl[j] = (int)dloc;
        si = (unsigned char)j;
        atomicAdd(&spCntD[dloc], 1u);
      }
    }
    spIdx[p] = si;
  }
  __syncthreads();

  int nsp = spCnt < SPCAP ? spCnt : SPCAP;
  {
    int dloc = tid >> 2, h = tid & 3;
    float erv = ((const float*)&erL[dloc])[h];
    float ebg = lrelu(0.f + erv);
    int nbg = (int)cntL[dloc] - (int)spCntD[dloc];
    float mx = (nbg > 0) ? ebg : -INFINITY;
    for (int j = 0; j < nsp; j++)
      if (spDl[j] == dloc)
        mx = fmaxf(mx, lrelu(elp[(size_t)spSrc[j]*4 + h] + erv));
    unsigned long long sm = 0ULL;
    float tbg = 0.f;
    if (nbg > 0){
      tbg = expf(ebg - mx);
      sm += (unsigned long long)nbg *
            (unsigned long long)llrint((double)tbg * 1073741824.0);
    }
    for (int j = 0; j < nsp; j++)
      if (spDl[j] == dloc){
        float es_ = lrelu(elp[(size_t)spSrc[j]*4 + h] + erv);
        sm += (unsigned long long)llrint((double)expf(es_ - mx) * 1073741824.0);
      }
    float smv = (float)((double)sm * (1.0/1073741824.0));
    mxF[dloc][h] = mx; smvF[dloc][h] = smv;
    avBg[dloc][h] = (cntL[dloc] > 0 && nbg > 0) ? (tbg / smv) : 0.f;
  }
  __syncthreads();
  for (int t = tid; t < nsp*4; t += 256){
    int j = t >> 2, h = t & 3;
    int dloc = spDl[j];
    float erv = ((const float*)&erL[dloc])[h];
    float es_ = lrelu(elp[(size_t)spSrc[j]*4 + h] + erv);
    avSp[j][h] = expf(es_ - mxF[dloc][h]) / smvF[dloc][h];
  }
  __syncthreads();

  int h = tid & 3, es = tid >> 2;
  unsigned long long top[NK];
#pragma unroll
  for (int k = 0; k < NK; k++) top[k] = 0ULL;
  for (int p = es; p < cnt; p += 64){
    unsigned long long v = ce[p];
    unsigned dloc = (unsigned)((v >> 16) & 0xFFULL);
    unsigned eid  = (unsigned)(v >> 24);
    unsigned char si = spIdx[p];
    float av = (si == 255) ? avBg[dloc][h] : avSp[si][h];
    unsigned long long key = ((unsigned long long)__float_as_uint(av) << 32)
                           | (unsigned long long)(~eid);
    if (key > top[NK-1]){
#pragma unroll
      for (int k = 0; k < NK; k++){
        unsigned long long hi = key > top[k] ? key : top[k];
        unsigned long long lo = key > top[k] ? top[k] : key;
        top[k] = hi; key = lo;
      }
    }
  }
  __syncthreads();

  int row = h*64 + es;
#pragma unroll
  for (int k = 0; k < NK; k++) cs[row][k] = top[k];
  __syncthreads();
  int w = tid >> 6, lane = tid & 63;
  unsigned long long mytop[NK];
#pragma unroll
  for (int k = 0; k < NK; k++) mytop[k] = cs[w*64 + lane][k];
  unsigned long long best = 0ULL; int bp = -1;
#pragma unroll
  for (int k = 0; k < NK; k++) if (mytop[k] > best){ best = mytop[k]; bp = k; }
  for (int r = 0; r < NK; r++){
    unsigned long long b = best; int srcl = lane;
#pragma unroll
    for (int off = 32; off > 0; off >>= 1){
      unsigned long long ob = __shfl_down(b, off, 64);
      int os = __shfl_down(srcl, off, 64);
      if (ob > b){ b = ob; srcl = os; }
    }
    b = __shfl(b, 0, 64); srcl = __shfl(srcl, 0, 64);
    if (lane == 0) cand[(((size_t)m*NH + w)*NCB + blockIdx.x)*NK + r] = b;
    if (lane == srcl && bp >= 0){
#pragma unroll
      for (int k = 0; k < NK; k++) if (k == bp) mytop[k] = 0ULL;
      best = 0ULL; bp = -1;
#pragma unroll
      for (int k = 0; k < NK; k++) if (mytop[k] > best){ best = mytop[k]; bp = k; }
    }
  }
}

// ---- merge level 1
__global__ __launch_bounds__(256) void k_merge1(
    const unsigned long long* __restrict__ cand,
    unsigned long long* __restrict__ cand2)
{
  int hh = blockIdx.x, m = blockIdx.y, z = blockIdx.z;
  int tid = threadIdx.x;
  const unsigned long long* cp = cand + ((size_t)m*NH + hh)*((size_t)NCB*NK);
  int start = z*SLW;
  int end = start + SLW; if (end > NCB*NK) end = NCB*NK;
  unsigned long long mykey = (start + tid < end) ? cp[start + tid] : 0ULL;

  __shared__ unsigned long long red[256];
  __shared__ int redpos[256];
  for (int r = 0; r < NK; r++){
    red[tid] = mykey; redpos[tid] = tid;
    __syncthreads();
    for (int st = 128; st > 0; st >>= 1){
      if (tid < st && red[tid+st] > red[tid]){ red[tid] = red[tid+st]; redpos[tid] = redpos[tid+st]; }
      __syncthreads();
    }
    if (tid == 0)
      cand2[(((size_t)m*NH + hh)*NSL + z)*NK + r] = red[0];
    int winner = redpos[0];
    __syncthreads();
    if (tid == winner) mykey = 0ULL;
  }
}

// ---- merge level 2: 8 blocks x 512 threads
__global__ __launch_bounds__(512) void k_merge2(
    const unsigned long long* __restrict__ cand2,
    unsigned long long* __restrict__ selg)
{
  int hh = blockIdx.x, m = blockIdx.y;
  int tid = threadIdx.x;
  const unsigned long long* cp = cand2 + ((size_t)m*NH + hh)*((size_t)NSL*NK);
  unsigned long long mykey = (tid < NSL*NK) ? cp[tid] : 0ULL;

  __shared__ unsigned long long red[512];
  __shared__ int redpos[512];
  for (int r = 0; r < NK; r++){
    red[tid] = mykey; redpos[tid] = tid;
    __syncthreads();
    for (int st = 256; st > 0; st >>= 1){
      if (tid < st && red[tid+st] > red[tid]){ red[tid] = red[tid+st]; redpos[tid] = redpos[tid+st]; }
      __syncthreads();
    }
    if (tid == 0)
      selg[((size_t)m*NH + hh)*NK + r] = red[0];
    int winner = redpos[0];
    __syncthreads();
    if (tid == winner) mykey = 0ULL;
  }
}

// ---- selA: scores + ballot slot assignment
__global__ __launch_bounds__(256) void k_selA(
    const unsigned long long* __restrict__ selg,
    const int* __restrict__ s0, const int* __restrict__ d0,
    const int* __restrict__ s1, const int* __restrict__ d1,
    const int* __restrict__ idsA,
    int* __restrict__ idsOut, int4* __restrict__ selinfo, int layer)
{
  int m = blockIdx.x;
  int tid = threadIdx.x;
  const int* sp = m ? s1 : s0;
  const int* dp = m ? d1 : d0;
  int wv = tid >> 6, lane = tid & 63;

  __shared__ float scL[NH][NK];
  __shared__ int snL[NH][NK], dL[NH][NK];
  __shared__ int slotOf[NH][NK], srcOf[NH][NK];

  if (tid < NH*NK){
    int h = tid / NK, k = tid % NK;
    unsigned long long s = selg[((size_t)m*NH + h)*NK + k];
    int e = (int)(~(unsigned)(s & 0xFFFFFFFFULL));
    snL[h][k] = sp[e];
    dL[h][k]  = dp[e];
  }
  __syncthreads();

  if (tid < NH){
    float v0 = __uint_as_float((unsigned)(selg[((size_t)m*NH + tid)*NK + 0] >> 32));
    float p[NK]; float sum = 0.f;
#pragma unroll
    for (int k = 0; k < NK; k++){
      float v = __uint_as_float((unsigned)(selg[((size_t)m*NH + tid)*NK + k] >> 32));
      p[k] = expf(v - v0); sum += p[k];
    }
#pragma unroll
    for (int k = 0; k < NK; k++) scL[tid][k] = p[k] / sum;
  }

  if (wv == 0){
    int myA = -1;
    if (layer) myA = idsA[m*64 + lane];
    int myid = -1;
    int cnt = 0;
    for (int h = 0; h < NH; h++){
      for (int k = 0; k < NK; k++){
        int sn = snL[h][k], d = dL[h][k];
        int srcslot = sn;
        bool ok = true;
        if (layer){
          unsigned long long mb = __ballot(myA == sn);
          if (mb) srcslot = __ffsll(mb) - 1;
          else ok = false;
        }
        int slot = -1;
        if (ok){
          unsigned long long mm = __ballot(lane < cnt && myid == d);
          if (mm) slot = __ffsll(mm) - 1;
          else { slot = cnt; if (lane == cnt) myid = d; cnt++; }
        }
        if (lane == 0){ slotOf[h][k] = slot; srcOf[h][k] = srcslot; }
      }
    }
    idsOut[m*64 + lane] = (lane < cnt) ? myid : -1;
  }
  __syncthreads();

  if (tid < NH*NK){
    int h = tid / NK, k = tid % NK;
    selinfo[((size_t)m*NH + h)*NK + k] =
        make_int4(snL[h][k], slotOf[h][k], srcOf[h][k], __float_as_int(scL[h][k]));
  }
}

// ---- selB: per (h,m) block — on-demand wh rows (layer 0), parallel dsum, exact-order scatter
__global__ __launch_bounds__(256) void k_selB(
    const int4* __restrict__ selinfo,
    const float* __restrict__ hmat, const float* __restrict__ Whm,
    const float* __restrict__ ftsrc,  // layer1: vals0
    const float* __restrict__ fcW,
    float* __restrict__ valsOut, int layer)
{
  int h = blockIdx.x, m = blockIdx.y;
  int tid = threadIdx.x;
  __shared__ int sn10[NK], slot10[NK], srcsl10[NK];
  __shared__ float sc10[NK];
  __shared__ float hs10[NK][260];
  __shared__ float whL10[NK][132];
  __shared__ float dsumL[NK][32];

  if (tid < NK){
    int4 si = selinfo[((size_t)m*NH + h)*NK + tid];
    sn10[tid] = si.x; slot10[tid] = si.y; srcsl10[tid] = si.z;
    sc10[tid] = __int_as_float(si.w);
  }
  __syncthreads();

  if (layer == 0){
    for (int t = tid; t < NK*64; t += 256){
      int e = t >> 6, k4 = t & 63;
      float4 v = ((const float4*)hmat)[(size_t)sn10[e]*64 + k4];
      *(float4*)&hs10[e][k4*4] = v;
    }
    __syncthreads();
    int w = tid & 127, rh = tid >> 7;
    float acc5[5];
#pragma unroll
    for (int i = 0; i < 5; i++) acc5[i] = 0.f;
    const float4* wp = (const float4*)&Whm[(size_t)w*IN_F];
    for (int k4 = 0; k4 < 64; k4++){
      float4 wv2 = wp[k4];
#pragma unroll
      for (int i = 0; i < 5; i++){
        float4 hv = *(const float4*)&hs10[rh + 2*i][k4*4];
        acc5[i] += hv.x*wv2.x; acc5[i] += hv.y*wv2.y;
        acc5[i] += hv.z*wv2.z; acc5[i] += hv.w*wv2.w;
      }
    }
#pragma unroll
    for (int i = 0; i < 5; i++) whL10[rh + 2*i][w] = acc5[i];
    __syncthreads();
  }

  for (int t = tid; t < NK*32; t += 256){
    int k = t >> 5, f = t & 31;
    float dsum = 0.f;
    if (slot10[k] >= 0){
      const float* x = layer ? (ftsrc + ((size_t)m*64 + srcsl10[k])*128) : &whL10[k][0];
      const float* wr = fcW + ((size_t)m*128 + h*OUTF + f)*128;
      for (int w = 0; w < 128; w++) dsum += x[w] * wr[w];
    }
    dsumL[k][f] = dsum;
  }
  __syncthreads();

  if (tid < OUTF){
    int f = tid;
    float* vals = valsOut + (size_t)m*64*128;
    for (int k = 0; k < NK; k++){
      int slot = slot10[k];
      if (slot < 0) continue;
      vals[(size_t)slot*128 + h*OUTF + f] += sc10[k] * dsumL[k][f];
    }
  }
}

// ---- elu on sparse rows; optionally compute layer-2 el2/er2 entries
__global__ __launch_bounds__(128) void k_elu2(
    const int* __restrict__ ids, float* __restrict__ vals,
    const float* __restrict__ plpr1,
    float* __restrict__ el2, float* __restrict__ er2, int doEl2)
{
  int slot = blockIdx.x, m = blockIdx.y, tid = threadIdx.x;
  float* row = vals + ((size_t)m*64 + slot)*128;
  float x = row[tid];
  row[tid] = x > 0.f ? x : expm1f(x);
  __syncthreads();
  if (!doEl2) return;
  int d = ids[m*64 + slot];
  if (d < 0) return;
  if (tid < 8){
    int lr = tid >> 2, hh = tid & 3;
    const float* P = plpr1 + (((size_t)m*2 + lr)*NH + hh)*128;
    float s = 0.f;
    for (int w = 0; w < 128; w++) s += row[w] * P[w];
    float* dp = lr ? er2 : el2;
    dp[((size_t)m*NN + d)*4 + hh] = s;
  }
}

// ---- semantic attention on special rows only (inlined first-occurrence dedupe)
__global__ __launch_bounds__(128) void k_final(
    const int* __restrict__ ids, const float* __restrict__ vals,
    const float* __restrict__ Wp1, const float* __restrict__ bp1, const float* __restrict__ Wp2,
    float c0, float c1, float* __restrict__ out)
{
  int j = blockIdx.x;
  int n = ids[j];
  if (n < 0) return;
  for (int q = 0; q < j; q++) if (ids[q] == n) return;
  int tid = threadIdx.x;
  __shared__ float z[2][128];
  __shared__ int slots[4];
  if (tid < 4){
    int sl = -1;
    const int* base = ids + tid*64;
    for (int q = 0; q < 64; q++) if (base[q] == n){ sl = q; break; }
    slots[tid] = sl;
  }
  __syncthreads();
#pragma unroll
  for (int m = 0; m < 2; m++){
    int sa = slots[m], sb = slots[2 + m];
    float av = sa >= 0 ? vals[((size_t)m*64 + sa)*128 + tid] : 0.f;
    float bv = sb >= 0 ? vals[((size_t)(2 + m)*64 + sb)*128 + tid] : 0.f;
    z[m][tid] = c0*av + c1*bv;
  }
  __syncthreads();
  float a0 = bp1[tid], a1 = a0;
  const float* wr = Wp1 + (size_t)tid*128;
  for (int w = 0; w < 128; w++){
    float wv = wr[w];
    a0 += z[0][w]*wv;
    a1 += z[1][w]*wv;
  }
  float t0 = tanhf(a0), t1 = tanhf(a1);
  float w2v = Wp2[tid];
  __shared__ float r0[128], r1[128];
  r0[tid] = t0*w2v; r1[tid] = t1*w2v;
  __syncthreads();
  for (int st = 64; st > 0; st >>= 1){
    if (tid < st){ r0[tid] += r0[tid+st]; r1[tid] += r1[tid+st]; }
    __syncthreads();
  }
  __shared__ float b0s, b1s;
  if (tid == 0){
    float w0 = r0[0], w1 = r1[0];
    float mxv = fmaxf(w0, w1);
    float e0 = expf(w0 - mxv), e1 = expf(w1 - mxv);
    float s = e0 + e1;
    b0s = e0/s; b1s = e1/s;
  }
  __syncthreads();
  out[(size_t)n*ND + tid] = b0s*z[0][tid] + b1s*z[1][tid];
}

extern "C" void kernel_launch(void* const* d_in, const int* in_sizes, int n_in,
                              void* d_out, int out_size, void* d_ws, size_t ws_size,
                              hipStream_t stream)
{
  const float* h    = (const float*)d_in[0];
  const int*   src0 = (const int*)d_in[1];
  const int*   dst0 = (const int*)d_in[2];
  const int*   src1 = (const int*)d_in[3];
  const int*   dst1 = (const int*)d_in[4];
  const float* Wh   = (const float*)d_in[5];
  const float* fc0  = (const float*)d_in[6];
  const float* al0  = (const float*)d_in[7];
  const float* ar0  = (const float*)d_in[8];
  const float* fc1  = (const float*)d_in[9];
  const float* al1  = (const float*)d_in[10];
  const float* ar1  = (const float*)d_in[11];
  const float* Wp1  = (const float*)d_in[12];
  const float* bp1  = (const float*)d_in[13];
  const float* Wp2  = (const float*)d_in[14];
  float* out = (float*)d_out;

  char* ws = (char*)d_ws;
  size_t off = 0;
  auto alloc = [&](size_t b){ size_t o = off; off = (off + b + 255) & ~(size_t)255; return o; };
  size_t o_el0    = alloc((size_t)NM*NN*4*4);
  size_t o_er0    = alloc((size_t)NM*NN*4*4);
  size_t o_plpr   = alloc(4096*4);
  size_t o_p2     = alloc(16*256*4);
  size_t o_cand   = alloc((size_t)NM*NH*NCB*NK*8);
  size_t o_cand2  = alloc((size_t)NM*NH*NSL*NK*8);
  size_t o_selg   = alloc((size_t)NM*NH*NK*8);
  size_t o_selinf = alloc((size_t)NM*NH*NK*16);
  size_t o_coarse = alloc((size_t)NM*NCB*CCAP*8);
  size_t o_zs     = off;                       // ---- zeroed region start
  size_t o_ccnt   = alloc((size_t)NM*NCB*4);
  size_t o_el2    = alloc((size_t)NM*NN*4*4);
  size_t o_er2    = alloc((size_t)NM*NN*4*4);
  size_t o_vals   = alloc((size_t)2*NM*64*128*4);
  size_t zlen = off - o_zs;                    // ---- zeroed region end
  size_t o_ids    = alloc((size_t)2*NM*64*4);
  (void)ws_size; (void)in_sizes; (void)n_in;

  float* el0p  = (float*)(ws + o_el0);
  float* er0p  = (float*)(ws + o_er0);
  float* plprp = (float*)(ws + o_plpr);
  float* p2p   = (float*)(ws + o_p2);
  unsigned long long* candp  = (unsigned long long*)(ws + o_cand);
  unsigned long long* cand2p = (unsigned long long*)(ws + o_cand2);
  unsigned long long* selgp  = (unsigned long long*)(ws + o_selg);
  int4* selinfp = (int4*)(ws + o_selinf);
  unsigned long long* coarsep = (unsigned long long*)(ws + o_coarse);
  unsigned* ccntp = (unsigned*)(ws + o_ccnt);
  float* el2p  = (float*)(ws + o_el2);
  float* er2p  = (float*)(ws + o_er2);
  float* valsp = (float*)(ws + o_vals);
  int*   idsp  = (int*)(ws + o_ids);
  float* vals0p = valsp;
  float* vals1p = valsp + (size_t)NM*64*128;
  int* ids0p = idsp;
  int* ids1p = idsp + NM*64;
  float* plpr1p = plprp + 2048;

  double x1 = 1.0 / (2.0 * sqrt(2.0));
  double ssum = 1.0 + x1;
  float c0 = (float)(1.0/ssum), c1 = (float)(x1/ssum);

  hipMemsetAsync(d_out, 0, (size_t)out_size*sizeof(float), stream);
  hipMemsetAsync(ws + o_zs, 0, zlen, stream);

  k_plpr<<<16, 256, 0, stream>>>(fc0, al0, ar0, fc1, al1, ar1, plprp);
  k_p2<<<16, 256, 0, stream>>>(plprp, Wh, p2p);
  k_el<<<(NN + 63)/64, 256, 0, stream>>>(h, p2p, el0p, er0p);

  k_part<<<dim3(256, NM), 256, 0, stream>>>(src0, dst0, src1, dst1, ccntp, coarsep);

  dim3 gf(NCB, NM);
  dim3 gm1(NH, NM, NSL);
  dim3 gm2(NH, NM);
  dim3 gb(NH, NM);
  dim3 ge(64, NM);

  // ---- layer 1
  k_fused<<<gf, 256, 0, stream>>>(ccntp, coarsep, el0p, er0p, candp);
  k_merge1<<<gm1, 256, 0, stream>>>(candp, cand2p);
  k_merge2<<<gm2, 512, 0, stream>>>(cand2p, selgp);
  k_selA<<<NM, 256, 0, stream>>>(selgp, src0, dst0, src1, dst1,
                                 (const int*)nullptr, ids0p, selinfp, 0);
  k_selB<<<gb, 256, 0, stream>>>(selinfp, h, Wh, (const float*)nullptr, fc0, vals0p, 0);
  k_elu2<<<ge, 128, 0, stream>>>(ids0p, vals0p, plpr1p, el2p, er2p, 1);

  // ---- layer 2 (sparsity-specialized fused kernel)
  k_fused2<<<gf, 256, 0, stream>>>(ccntp, coarsep, el2p, er2p, ids0p, candp);
  k_merge1<<<gm1, 256, 0, stream>>>(candp, cand2p);
  k_merge2<<<gm2, 512, 0, stream>>>(cand2p, selgp);
  k_selA<<<NM, 256, 0, stream>>>(selgp, src0, dst0, src1, dst1,
                                 ids0p, ids1p, selinfp, 1);
  k_selB<<<gb, 256, 0, stream>>>(selinfp, h, Wh, vals0p, fc1, vals1p, 1);
  k_elu2<<<ge, 128, 0, stream>>>(ids1p, vals1p, plpr1p, el2p, er2p, 0);

  // ---- semantic attention on the sparse union
  k_final<<<256, 128, 0, stream>>>(idsp, valsp, Wp1, bp1, Wp2, c0, c1, out);
}